// Round 7
// baseline (390.296 us; speedup 1.0000x reference)
//
#include <hip/hip_runtime.h>
#include <math.h>

#define BB 64
#define TT 4096
#define CC 64

constexpr int L0v = 2048, U0v = 3069, V0v = 1535, P0v = 2048;
constexpr int L1v = 1024, U1v = 1533, V1v = 767,  P1v = 1024;
constexpr int OUTL = 6144;
constexpr long NTOT = (long)BB * TT * CC;
#define VB 30         // pool outputs per tile (-> 21 a's, 42 E0 + 21 E1 = 63 E-rows)
#define NB0 52        // ceil(V0v/VB)
#define NB1 26        // ceil(V1v/VB)
#define NTILE ((NB0 + NB1) * 64)
#define SRTOT 87      // staged rows: 44 (X0) + 43 (X1)
#define XSTR 72       // ushort stride per staged row (multiple of 8; 16B-aligned rows)
#define XPL  (SRTOT * XSTR)   // 6264 ushorts per split-plane
#define RSTR 65       // E-buffer stride (words)
#define EROWS 63

using short8  = __attribute__((ext_vector_type(8))) short;
using floatx4 = __attribute__((ext_vector_type(4))) float;

// ---- bf16 round-to-nearest-even ----
__device__ inline unsigned bf16rn(float f) {
  unsigned u = __float_as_uint(f);
  return (u + 0x7fffu + ((u >> 16) & 1u)) >> 16;
}
__device__ inline void bf16split3(float x, unsigned short& h, unsigned short& m,
                                  unsigned short& l) {
  unsigned uh = bf16rn(x); h = (unsigned short)uh;
  float r1 = x - __uint_as_float(uh << 16);
  unsigned um = bf16rn(r1); m = (unsigned short)um;
  l = (unsigned short)bf16rn(r1 - __uint_as_float(um << 16));
}

// ---- transpose x[b][t][c] -> xtr[b][c][t], fused global sum/sumsq ----
__global__ __launch_bounds__(256) void transpose_stats(const float* __restrict__ x,
                                                       float* __restrict__ xtr,
                                                       double* __restrict__ part) {
  __shared__ float tile[64][65];
  __shared__ double sred[8];
  const int tt = blockIdx.x;
  const int b = blockIdx.y;
  const int t0 = tt * 64;
  const long xbase = (long)b * TT * CC + (long)t0 * CC;
  const int tid = threadIdx.x;
  double a = 0, q = 0;
  {
    const int c4 = (tid & 15) * 4;
    const int r0 = tid >> 4;
#pragma unroll
    for (int rr = 0; rr < 4; rr++) {
      int r = r0 + rr * 16;
      float4 v = *(const float4*)&x[xbase + r * 64 + c4];
      tile[r][c4] = v.x; tile[r][c4 + 1] = v.y;
      tile[r][c4 + 2] = v.z; tile[r][c4 + 3] = v.w;
      a += (double)v.x + (double)v.y + (double)v.z + (double)v.w;
      q += (double)v.x * v.x + (double)v.y * v.y + (double)v.z * v.z + (double)v.w * v.w;
    }
  }
  __syncthreads();
  {
    const int t4 = (tid & 15) * 4;
    const int c0 = tid >> 4;
#pragma unroll
    for (int cc = 0; cc < 4; cc++) {
      int c = c0 + cc * 16;
      float4 v;
      v.x = tile[t4][c]; v.y = tile[t4 + 1][c];
      v.z = tile[t4 + 2][c]; v.w = tile[t4 + 3][c];
      *(float4*)&xtr[((long)(b * 64 + c)) * TT + t0 + t4] = v;
    }
  }
  for (int off = 32; off > 0; off >>= 1) {
    a += __shfl_down(a, off);
    q += __shfl_down(q, off);
  }
  if ((tid & 63) == 0) { sred[(tid >> 6) * 2] = a; sred[(tid >> 6) * 2 + 1] = q; }
  __syncthreads();
  if (tid == 0) {
    part[(b * 64 + tt) * 2]     = sred[0] + sred[2] + sred[4] + sred[6];
    part[(b * 64 + tt) * 2 + 1] = sred[1] + sred[3] + sred[5] + sred[7];
  }
}

// ---------------- closed-form index helpers ----------------
__device__ __host__ inline int pad_idx(int p, int brk, int dup, int sub) {
  if (p < brk) { int q = p / 3; int r = p - 3 * q; return 2 * q + (r == 2 ? 1 : 0); }
  if (p < brk + 2) return dup;
  return p - sub;
}

__device__ inline int fmap_code(int k) {
  if (k == 0) return 2048 + 0;
  if (k == 1) return 0;
  if (k < 5462) {
    int m = k - 2;
    int c = m / 12;
    int j = m - 12 * c;
    if (j <= 3)  return 2048 + (1 + 9 * c + j);
    if (j == 4)  return 1 + 3 * c;
    if (j <= 8)  return 2048 + (9 * c + j);
    if (j == 9)  return 2 + 3 * c;
    if (j == 10) return 2048 + (9 + 9 * c);
    return 3 + 3 * c;
  }
  return k - 4096;
}

// ---- merged prep: block 0 = stats_final, 1..64 = weight_norm(bf16 3-split),
//      65..88 = codes ----
// Weights go out TRANSPOSED: wt*[o][k] with k = tap*64 + ch (192 per o), as
// 3-way bf16 split planes h/m/l (so w = h+m+l to ~2^-23 rel).
__global__ __launch_bounds__(256) void prep(const double* __restrict__ part,
                                            double* __restrict__ stats,
                                            const float* __restrict__ v,
                                            const float* __restrict__ g,
                                            unsigned short* __restrict__ wth,
                                            unsigned short* __restrict__ wtm,
                                            unsigned short* __restrict__ wtl,
                                            int* __restrict__ codes) {
  const int blk = blockIdx.x;
  const int tid = threadIdx.x;
  if (blk == 0) {
    __shared__ double s1[256], s2[256];
    double a = 0, q = 0;
    for (int i = tid; i < 4096; i += 256) { a += part[2 * i]; q += part[2 * i + 1]; }
    s1[tid] = a; s2[tid] = q;
    __syncthreads();
    for (int s = 128; s > 0; s >>= 1) {
      if (tid < s) { s1[tid] += s1[tid + s]; s2[tid] += s2[tid + s]; }
      __syncthreads();
    }
    if (tid == 0) {
      double n = (double)NTOT;
      double mean = s1[0] / n;
      double var = (s2[0] - s1[0] * s1[0] / n) / (n - 1.0);
      stats[0] = mean; stats[1] = sqrt(var);
      stats[2] = 0.8 / mean;
      stats[3] = 0.8 / sqrt(var);
    }
  } else if (blk <= 64) {
    int o = blk - 1;
    __shared__ float red[256];
    __shared__ float scale;
    float vv = (tid < 192) ? v[o * 192 + tid] : 0.f;
    red[tid] = vv * vv;
    __syncthreads();
    for (int s = 128; s > 0; s >>= 1) {
      if (tid < s) red[tid] += red[tid + s];
      __syncthreads();
    }
    if (tid == 0) scale = g[o] / sqrtf(red[0]);
    __syncthreads();
    if (tid < 192) {
      int i = tid / 3, k = tid - 3 * i;     // v layout: [o][i][k]
      float w = scale * vv;                 // w[k][i][o]
      unsigned short h, m, l;
      bf16split3(w, h, m, l);
      int kk = o * 192 + k * 64 + i;        // wt*[o][k*64+i]
      wth[kk] = h; wtm[kk] = m; wtl[kk] = l;
    }
  } else {
    int k = (blk - 65) * 256 + tid;
    if (k < OUTL) {
      int s = fmap_code(k);
      int type, xi, yi = 0;
      if (s < 2048) {
        if ((s & 1) == 0) { type = 0; xi = 2 * s; }
        else { int p = s >> 1; yi = pad_idx(p, 768, 512, 257); xi = 4 * p + 3; type = 2; }
      } else {
        int p = s - 2048;
        if ((p & 1) == 0) { type = 0; xi = p; }
        else { int q = p >> 1; yi = pad_idx(q, 1536, 1024, 513); xi = 2 * q + 1; type = 1; }
      }
      codes[k] = type | (xi << 2) | (yi << 14);
    }
  }
}

// ---- fused conv (stride2, dil3) + bias + maxpool(3,s2,p1) + elu + gauss + bn-partials ----
// MFMA version.  Per tile: E[63x64] = X[63x192] . W[192x64]  (K=192).
// fp32 has no MFMA; single bf16 is fatal here (ivm ~ +-3000 amplifies E1, y
// lives in a |E1|<~0.002 window), so 3-way bf16 split: X=Xh+Xm+Xl, W likewise,
// keep the 6 products >= 2^-16 (hh,hm,mh,hl,lh,mm) -> split error ~1e-9 rel.
// Layout safety: C/D map is the HW-verified col=lane&15, row=4*(lane>>4)+reg;
// A/B k-slot mapping cancels because A and B load k-elements with the SAME
// (lane>>4,j) bijection (any HW k-permutation drops out of the dot product).
// Wave w owns M-tile rows 16w..16w+15; 4 N-tiles x 6 K-steps x 6 splits.
__global__ __launch_bounds__(256, 4) void conv_pool(
    const float* __restrict__ x,
    const unsigned short* __restrict__ wth,
    const unsigned short* __restrict__ wtm,
    const unsigned short* __restrict__ wtl,
    const float* __restrict__ cbias, const double* __restrict__ stats,
    float* __restrict__ y10, float* __restrict__ y11,
    float* __restrict__ part) {
  const int b = blockIdx.x;
  const int jb = blockIdx.y;
  const bool lev0 = jb < NB0;
  const int v0 = (lev0 ? jb : jb - NB0) * VB;
  const int L = lev0 ? L0v : L1v;
  const int U = lev0 ? U0v : U1v;
  const int V = lev0 ? V0v : V1v;
  const int mult = lev0 ? 2 : 4;
  const int off1 = lev0 ? 1 : 3;
  const int mid = lev0 ? 1024 : 512;
  float* __restrict__ y1 = lev0 ? y10 : y11;

  const int tid = threadIdx.x;
  const int lane = tid & 63;
  const int w = tid >> 6;

  const int a0 = (v0 == 0) ? 0 : (2 * v0 - 1) / 3;

  // Xs: 3 bf16 split planes [87][72] ushort = 37584 B.
  // Overlay after MFMA: cbf[63][65] f32 + red[512] f32 (18432 B).
  __shared__ __align__(16) unsigned short Xs[3 * XPL];
  float* cbf = (float*)Xs;
  float* red = (float*)Xs + 4096;

  const float ivm = (float)stats[2];
  const float ivs = (float)stats[3];
  const long xbase = (long)b * TT * CC;

  // ---- stage both raw streams as 3-way bf16 split, rows [d][ch] ----
  for (int idx = tid; idx < SRTOT * 16; idx += 256) {
    int d = idx >> 4, g = idx & 15;
    int T = (d < 44) ? (2 * a0 + d) : (2 * a0 + d - 44);
    int Tc = min(max(T, 0), L - 1);
    long row = (long)(mult * Tc) * CC + ((d < 44) ? 0 : off1) * CC;
    float4 vr = *(const float4*)&x[xbase + row + g * 4];
    ushort4 hv, mv, lv;
    bf16split3(vr.x, hv.x, mv.x, lv.x);
    bf16split3(vr.y, hv.y, mv.y, lv.y);
    bf16split3(vr.z, hv.z, mv.z, lv.z);
    bf16split3(vr.w, hv.w, mv.w, lv.w);
    int off = d * XSTR + g * 4;
    *(ushort4*)&Xs[off]           = hv;
    *(ushort4*)&Xs[XPL + off]     = mv;
    *(ushort4*)&Xs[2 * XPL + off] = lv;
  }
  __syncthreads();

  // ---- MFMA phase ----
  const int r16 = lane & 15;
  const int hgrp = lane >> 4;
  const int row = 16 * w + r16;                 // M row (E-row index)
  const int rho = (row <= 41) ? row : ((row == 63) ? 0 : (2 * row - 40));

  floatx4 acc[4];
#pragma unroll
  for (int n = 0; n < 4; n++) acc[n] = floatx4{0.f, 0.f, 0.f, 0.f};

#pragma unroll 1
  for (int s = 0; s < 6; s++) {
    const int tap = s >> 1, chb = (s & 1) * 32;
    const int offA = (rho + tap) * XSTR + chb + hgrp * 8;
    short8 ah = *(const short8*)&Xs[offA];
    short8 am = *(const short8*)&Xs[XPL + offA];
    short8 al = *(const short8*)&Xs[2 * XPL + offA];
    const int offB = r16 * 192 + s * 32 + hgrp * 8;
#pragma unroll
    for (int n = 0; n < 4; n++) {
      const int ob = offB + n * 16 * 192;
      short8 bh = *(const short8*)&wth[ob];
      short8 bm = *(const short8*)&wtm[ob];
      short8 bl = *(const short8*)&wtl[ob];
      acc[n] = __builtin_amdgcn_mfma_f32_16x16x32_bf16(ah, bh, acc[n], 0, 0, 0);
      acc[n] = __builtin_amdgcn_mfma_f32_16x16x32_bf16(ah, bm, acc[n], 0, 0, 0);
      acc[n] = __builtin_amdgcn_mfma_f32_16x16x32_bf16(am, bh, acc[n], 0, 0, 0);
      acc[n] = __builtin_amdgcn_mfma_f32_16x16x32_bf16(ah, bl, acc[n], 0, 0, 0);
      acc[n] = __builtin_amdgcn_mfma_f32_16x16x32_bf16(al, bh, acc[n], 0, 0, 0);
      acc[n] = __builtin_amdgcn_mfma_f32_16x16x32_bf16(am, bm, acc[n], 0, 0, 0);
    }
  }

  __syncthreads();   // X planes dead; overlay E-buffer cbf[63][65]
#pragma unroll
  for (int n = 0; n < 4; n++) {
#pragma unroll
    for (int r = 0; r < 4; r++) {
      int er = 16 * w + 4 * hgrp + r;          // C/D row (verified mapping)
      if (er < EROWS)
        cbf[er * RSTR + n * 16 + r16] = acc[n][r];
    }
  }
  __syncthreads();

  // ---- combine + pool + elu + gauss + bn partials ----
  // E-row index: E0[2a] -> 2*ai ; E0[2a+1] -> 2*ai+1 ; E1[2a] -> 42+ai
  const int o = tid >> 2;
  const float bias = cbias[o];
  float a1 = 0.f, a2 = 0.f;
  for (int vq = tid & 3; vq < VB; vq += 4) {
    int v = v0 + vq;
    if (v < V) {
      float m3 = -INFINITY;
#pragma unroll
      for (int p = 0; p < 3; p++) {
        int u = 2 * v - 1 + p;
        float mv = -INFINITY;
        if (u >= 0 && u < U) {
          int a = u / 3;
          int r = u - 3 * a;
          int ai = a - a0;
          if (r == 2) {
            mv = cbf[(2 * ai + 1) * RSTR + o] + bias;
          } else {
            float e1 = cbf[(42 + ai) * RSTR + o];
            float e0 = cbf[(2 * ai) * RSTR + o];
            mv = fmaf(r ? ivs : ivm, e1, fmaf(0.2f, e0, bias));
          }
        }
        m3 = fmaxf(m3, mv);
      }
      float e = (m3 > 0.f) ? m3 : (expf(m3) - 1.f);
      float y = expf(-0.5f * e * e);
      y1[(long)(b * 64 + o) * V + v] = y;
      float wv = (v < mid) ? (float)(2 - (v & 1)) : ((v == mid) ? 2.f : 1.f);
      a1 += wv * y;
      a2 += wv * y * y;
    }
  }
  red[o * 4 + (tid & 3)] = a1;
  red[256 + o * 4 + (tid & 3)] = a2;
  __syncthreads();
  if (tid < 64) {
    float s1 = red[tid * 4] + red[tid * 4 + 1] + red[tid * 4 + 2] + red[tid * 4 + 3];
    float s2 = red[256 + tid * 4] + red[256 + tid * 4 + 1] + red[256 + tid * 4 + 2] + red[256 + tid * 4 + 3];
    long tile = (long)jb * 64 + b;
    part[tile * 128 + tid * 2] = s1;
    part[tile * 128 + tid * 2 + 1] = s2;
  }
}

// ---- bn reduce over per-tile partials -> affine coefficients z = A*y + B ----
__global__ __launch_bounds__(256) void bn_reduce(const float* __restrict__ part,
                                                 const float* __restrict__ gamma,
                                                 const float* __restrict__ beta,
                                                 float* __restrict__ cf0,
                                                 float* __restrict__ cf1) {
  const int bc = blockIdx.x;          // 0..127
  const int lev = bc >> 6, c = bc & 63;
  const long t_lo = lev ? (long)NB0 * 64 : 0;
  const long t_hi = lev ? (long)(NB0 + NB1) * 64 : (long)NB0 * 64;
  const int tid = threadIdx.x;
  double a = 0, q = 0;
  for (long t = t_lo + tid; t < t_hi; t += 256) {
    a += part[t * 128 + c * 2];
    q += part[t * 128 + c * 2 + 1];
  }
  __shared__ double s1[256], s2[256];
  s1[tid] = a; s2[tid] = q;
  __syncthreads();
  for (int s = 128; s > 0; s >>= 1) {
    if (tid < s) { s1[tid] += s1[tid + s]; s2[tid] += s2[tid + s]; }
    __syncthreads();
  }
  if (tid == 0) {
    double n = (double)BB * (lev ? P1v : P0v);
    double mu = s1[0] / n;
    double var = s2[0] / n - mu * mu;
    float rsig = 1.0f / sqrtf((float)var + 1e-5f);
    float A = gamma[c] * rsig;
    float Bv = beta[c] - (float)mu * A;
    float* cf = lev ? cf1 : cf0;
    cf[2 * c] = A;
    cf[2 * c + 1] = Bv;
  }
}

// ---- fused finalize + sew-up gather, LDS-staged ----
__global__ __launch_bounds__(256) void final_fused(
    const float* __restrict__ xtr, const float* __restrict__ y10,
    const float* __restrict__ y11, const float* __restrict__ cf0,
    const float* __restrict__ cf1, const int* __restrict__ codes,
    float* __restrict__ out) {
  const int bc = blockIdx.x;
  const int c = bc & 63;
  const int tid = threadIdx.x;
  __shared__ float xs[4096];
  __shared__ float y0s[1536];
  __shared__ float y1s[768];

  const float* xr = xtr + (long)bc * TT;
  for (int i = tid; i < 1024; i += 256)
    *(float4*)&xs[i * 4] = *(const float4*)&xr[i * 4];
  const float* y0r = y10 + (long)bc * V0v;
  for (int i = tid; i < 384; i += 256) {
    if (i < 383) *(float4*)&y0s[i * 4] = *(const float4*)&y0r[i * 4];
    else { y0s[1532] = y0r[1532]; y0s[1533] = y0r[1533]; y0s[1534] = y0r[1534]; }
  }
  const float* y1r = y11 + (long)bc * V1v;
  for (int i = tid; i < 192; i += 256) {
    if (i < 191) *(float4*)&y1s[i * 4] = *(const float4*)&y1r[i * 4];
    else { y1s[764] = y1r[764]; y1s[765] = y1r[765]; y1s[766] = y1r[766]; }
  }
  __syncthreads();

  const float A0 = cf0[2 * c], B0 = cf0[2 * c + 1];
  const float A1 = cf1[2 * c], B1 = cf1[2 * c + 1];
  float* orow = out + (long)bc * OUTL;
#pragma unroll 4
  for (int i = 0; i < 24; i++) {
    int k = i * 256 + tid;
    int code = codes[k];
    int type = code & 3;
    int xi = (code >> 2) & 4095;
    int yi = code >> 14;
    float xv = xs[xi];
    float yv = (type == 2) ? y1s[yi] : y0s[yi];
    float A = (type == 0) ? 0.f : ((type == 2) ? A1 : A0);
    float Bv = (type == 0) ? 0.f : ((type == 2) ? B1 : B0);
    float z = fmaf(A, yv, Bv);
    float e = (z > 0.f) ? z : (expf(z) - 1.f);
    orow[k] = xv + e;
  }
}

extern "C" void kernel_launch(void* const* d_in, const int* in_sizes, int n_in,
                              void* d_out, int out_size, void* d_ws, size_t ws_size,
                              hipStream_t stream) {
  const float* x   = (const float*)d_in[0];
  const float* cv  = (const float*)d_in[1];
  const float* cg  = (const float*)d_in[2];
  const float* cb  = (const float*)d_in[3];
  const float* gam = (const float*)d_in[4];
  const float* bet = (const float*)d_in[5];
  float* out = (float*)d_out;

  char* ws = (char*)d_ws;
  size_t cur = 0;
  auto alloc = [&](size_t bytes) -> char* {
    char* p = ws + cur;
    cur = (cur + bytes + 255) & ~(size_t)255;
    return p;
  };
  double* part   = (double*)alloc(4096 * 2 * sizeof(double));
  double* stats  = (double*)alloc(4 * sizeof(double));
  unsigned short* wth = (unsigned short*)alloc(64 * 192 * sizeof(unsigned short));
  unsigned short* wtm = (unsigned short*)alloc(64 * 192 * sizeof(unsigned short));
  unsigned short* wtl = (unsigned short*)alloc(64 * 192 * sizeof(unsigned short));
  float*  bnp    = (float*)alloc((size_t)NTILE * 128 * sizeof(float));
  float*  cf0    = (float*)alloc(128 * sizeof(float));
  float*  cf1    = (float*)alloc(128 * sizeof(float));
  int*    codes  = (int*)alloc(OUTL * sizeof(int));
  float*  xtr    = (float*)alloc((size_t)BB * CC * TT * sizeof(float));
  float*  y10    = (float*)alloc((size_t)4096 * V0v * sizeof(float));
  float*  y11    = (float*)alloc((size_t)4096 * V1v * sizeof(float));

  transpose_stats<<<dim3(64, 64), 256, 0, stream>>>(x, xtr, part);
  prep<<<89, 256, 0, stream>>>(part, stats, cv, cg, wth, wtm, wtl, codes);

  conv_pool<<<dim3(64, NB0 + NB1), 256, 0, stream>>>(
      x, wth, wtm, wtl, cb, stats, y10, y11, bnp);

  bn_reduce<<<128, 256, 0, stream>>>(bnp, gam, bet, cf0, cf1);

  final_fused<<<4096, 256, 0, stream>>>(xtr, y10, y11, cf0, cf1, codes, out);
}